// Round 13
// baseline (942.123 us; speedup 1.0000x reference)
//
#include <hip/hip_runtime.h>
#include <stdint.h>

#define Bq 8192
#define Dq 1024
#define Hq 1024
#define GROUP 2
#define NGROUP (Dq / GROUP)

typedef __fp16 half2_t __attribute__((ext_vector_type(2)));

static constexpr float NLOG2E = -1.4426950408889634f;

// async global->LDS, 16B/lane; lds dst is wave-uniform base (+ lane*16 by HW)
__device__ __forceinline__ void gl_lds16(const void* g, void* l) {
  __builtin_amdgcn_global_load_lds(
      (const __attribute__((address_space(1))) uint32_t*)g,
      (__attribute__((address_space(3))) uint32_t*)l, 16, 0, 0);
}

template <int CTRL>
__device__ __forceinline__ float dppadd(float v) {
  const int x = __builtin_bit_cast(int, v);
  const int y = __builtin_amdgcn_update_dpp(x, x, CTRL, 0xF, 0xF, false);
  return v + __builtin_bit_cast(float, y);
}

template <int OFF>
__device__ __forceinline__ float swzadd(float v) {
  const int y = __builtin_amdgcn_ds_swizzle(__builtin_bit_cast(int, v), OFF);
  return v + __builtin_bit_cast(float, y);
}

// Eh[d][h] = fp16 e^{-W[h][d]}   (W is (H,D) row-major)
__global__ __launch_bounds__(256) void prepE(const float* __restrict__ W,
                                             __fp16* __restrict__ Eh) {
  __shared__ float tile[32][33];
  const int tx = threadIdx.x, ty = threadIdx.y;
  const int bx = blockIdx.x, by = blockIdx.y;  // bx: d tile, by: h tile
#pragma unroll
  for (int i = 0; i < 4; ++i)
    tile[ty + i * 8][tx] = W[(size_t)(by * 32 + ty + i * 8) * Dq + bx * 32 + tx];
  __syncthreads();
#pragma unroll
  for (int i = 0; i < 4; ++i) {
    const int d = bx * 32 + ty + i * 8;
    const int h = by * 32 + tx;
    Eh[(size_t)d * Hq + h] = (__fp16)exp2f(tile[tx][ty + i * 8] * NLOG2E);
  }
}

// Vh = fp16(V * -log2e)
__global__ __launch_bounds__(256) void convV(const float* __restrict__ V,
                                             uint32_t* __restrict__ Vh) {
  const int i = blockIdx.x * 256 + threadIdx.x;
  const float4 v = reinterpret_cast<const float4*>(V)[i];
  half2_t h0 = __builtin_amdgcn_cvt_pkrtz(v.x * NLOG2E, v.y * NLOG2E);
  half2_t h1 = __builtin_amdgcn_cvt_pkrtz(v.z * NLOG2E, v.w * NLOG2E);
  uint2 pk;
  pk.x = __builtin_bit_cast(uint32_t, h0);
  pk.y = __builtin_bit_cast(uint32_t, h1);
  reinterpret_cast<uint2*>(Vh)[i] = pk;
}

// Block = 4 batch rows (4 waves x 1). Lane owns h = 8*lane + 512*j (j=0,1).
// State: y = 1+e^{-a} (half2 x8), h = 1/y (half2 x8, Newton-tracked).
__global__ __launch_bounds__(256, 8) void nade_fwd(
    const float* __restrict__ x, const uint32_t* __restrict__ Vh,
    const float* __restrict__ bvec, const uint32_t* __restrict__ Eh,
    const float* __restrict__ cvec, float* __restrict__ out) {
  __shared__ __align__(16) uint32_t Vs[2][GROUP][Hq / 2];  // fp16 pairs, 8 KB
  __shared__ __align__(16) uint32_t Es[2][GROUP][Hq / 2];  // fp16 pairs, 8 KB

  const int tid = threadIdx.x;
  const int wave = tid >> 6;
  const int lane = tid & 63;
  const int b0 = blockIdx.x * 4 + wave;  // this wave's batch row

  // ---- init: y = 1 + 2^{c*-log2e}, h = 1/y ----
  half2_t yy[8], hh[8];
#pragma unroll
  for (int q = 0; q < 2; ++q) {
    float cv[8];
    *reinterpret_cast<float4*>(&cv[0]) =
        *reinterpret_cast<const float4*>(&cvec[512 * q + 8 * lane]);
    *reinterpret_cast<float4*>(&cv[4]) =
        *reinterpret_cast<const float4*>(&cvec[512 * q + 8 * lane + 4]);
#pragma unroll
    for (int j = 0; j < 4; ++j) {
      const float y0 = 1.0f + __builtin_amdgcn_exp2f(cv[2 * j] * NLOG2E);
      const float y1 = 1.0f + __builtin_amdgcn_exp2f(cv[2 * j + 1] * NLOG2E);
      yy[4 * q + j] = __builtin_amdgcn_cvt_pkrtz(y0, y1);
      hh[4 * q + j] = __builtin_amdgcn_cvt_pkrtz(
          __builtin_amdgcn_rcpf(y0), __builtin_amdgcn_rcpf(y1));
    }
  }

  // ---- staging: rows [d0, d0+2): V 4KB + E 4KB, each one gl_lds16 sweep ----
  auto stage = [&](int d0, int buf) {
    gl_lds16((const char*)Vh + (size_t)d0 * 2048 + tid * 16,
             (char*)&Vs[buf][0][0] + wave * 1024);
    gl_lds16((const char*)Eh + (size_t)d0 * 2048 + tid * 16,
             (char*)&Es[buf][0][0] + wave * 1024);
  };

  stage(0, 0);

  unsigned long long xm = 0;
  float breg = 0.f;
  float po0, po1, po2, po3;
  const half2_t one2 = {(__fp16)1.0f, (__fp16)1.0f};
  const half2_t two2 = {(__fp16)2.0f, (__fp16)2.0f};

  __syncthreads();  // group 0 staged

#define STEP(CUR, SS, D, PO)                                                 \
  {                                                                          \
    const int dl = (D)&63;                                                   \
    const char* vp = (const char*)&Vs[0][0][0] + (CUR * GROUP + SS) * 2048;  \
    const uint4 v0 = *reinterpret_cast<const uint4*>(vp + 16 * lane);        \
    const uint4 v1 = *reinterpret_cast<const uint4*>(vp + 1024 + 16 * lane); \
    half2_t vh[8];                                                           \
    vh[0] = __builtin_bit_cast(half2_t, v0.x);                               \
    vh[1] = __builtin_bit_cast(half2_t, v0.y);                               \
    vh[2] = __builtin_bit_cast(half2_t, v0.z);                               \
    vh[3] = __builtin_bit_cast(half2_t, v0.w);                               \
    vh[4] = __builtin_bit_cast(half2_t, v1.x);                               \
    vh[5] = __builtin_bit_cast(half2_t, v1.y);                               \
    vh[6] = __builtin_bit_cast(half2_t, v1.z);                               \
    vh[7] = __builtin_bit_cast(half2_t, v1.w);                               \
    float s = 0.f;                                                           \
    _Pragma("unroll") for (int p = 0; p < 8; ++p) {                          \
      s = __builtin_amdgcn_fdot2(hh[p], vh[p], s, false);                    \
    }                                                                        \
    s = dppadd<0xB1>(s);   /* xor1 */                                        \
    s = dppadd<0x4E>(s);   /* xor2 */                                        \
    s = swzadd<0x101F>(s); /* xor4 */                                        \
    s = swzadd<0x201F>(s); /* xor8 */                                        \
    s = swzadd<0x401F>(s); /* xor16 */                                       \
    s += __shfl_xor(s, 32);                                                  \
    const float bd = __builtin_bit_cast(                                     \
        float, __builtin_amdgcn_readlane(__builtin_bit_cast(int, breg), dl)); \
    PO = __builtin_amdgcn_rcpf(1.0f + __builtin_amdgcn_exp2f(bd + s));       \
    if ((xm >> dl) & 1) {                                                    \
      const char* ep = (const char*)&Es[0][0][0] + (CUR * GROUP + SS) * 2048; \
      const uint4 e0 = *reinterpret_cast<const uint4*>(ep + 16 * lane);      \
      const uint4 e1 = *reinterpret_cast<const uint4*>(ep + 1024 + 16 * lane); \
      half2_t e[8];                                                          \
      e[0] = __builtin_bit_cast(half2_t, e0.x);                              \
      e[1] = __builtin_bit_cast(half2_t, e0.y);                              \
      e[2] = __builtin_bit_cast(half2_t, e0.z);                              \
      e[3] = __builtin_bit_cast(half2_t, e0.w);                              \
      e[4] = __builtin_bit_cast(half2_t, e1.x);                              \
      e[5] = __builtin_bit_cast(half2_t, e1.y);                              \
      e[6] = __builtin_bit_cast(half2_t, e1.z);                              \
      e[7] = __builtin_bit_cast(half2_t, e1.w);                              \
      _Pragma("unroll") for (int j = 0; j < 8; ++j) {                        \
        const half2_t t = yy[j] - one2;                                      \
        yy[j] = t * e[j] + one2;            /* y' = (y-1)E + 1 */            \
        const half2_t nt = two2 - hh[j] * yy[j];                             \
        hh[j] = hh[j] * nt;                 /* Newton: h' = h(2-hy) */       \
      }                                                                      \
    }                                                                        \
  }

  for (int gg = 0; gg < NGROUP; gg += 2) {
    // every 64 d-steps: x bitmask via ballot (uniform->SGPR), pre-scaled b
    if ((gg & 31) == 0) {
      const float xv = x[(size_t)b0 * Dq + 2 * gg + lane];
      xm = __ballot(xv != 0.0f);
      breg = bvec[2 * gg + lane] * NLOG2E;
    }

    stage(2 * (gg + 1), 1);  // prefetch group gg+1 -> buf1
    STEP(0, 0, 2 * gg, po0)
    STEP(0, 1, 2 * gg + 1, po1)
    __syncthreads();  // buf1 staged; buf0 reads done

    if (gg + 2 < NGROUP) stage(2 * (gg + 2), 0);  // prefetch -> buf0
    STEP(1, 0, 2 * gg + 2, po2)
    STEP(1, 1, 2 * gg + 3, po3)
    __syncthreads();  // buf0 staged; buf1 reads done

    if (lane == 0) {
      *reinterpret_cast<float4*>(&out[(size_t)b0 * Dq + 2 * gg]) =
          make_float4(po0, po1, po2, po3);
    }
  }
#undef STEP
}

extern "C" void kernel_launch(void* const* d_in, const int* in_sizes, int n_in,
                              void* d_out, int out_size, void* d_ws, size_t ws_size,
                              hipStream_t stream) {
  (void)in_sizes; (void)n_in; (void)out_size; (void)ws_size;
  const float* x = (const float*)d_in[0];   // (B,D)
  const float* V = (const float*)d_in[1];   // (D,H)
  const float* b = (const float*)d_in[2];   // (D)
  const float* W = (const float*)d_in[3];   // (H,D)
  const float* c = (const float*)d_in[4];   // (H)
  float* out = (float*)d_out;               // (B,D)
  __fp16* Eh = (__fp16*)d_ws;                                   // 2 MB fp16
  uint32_t* Vh = (uint32_t*)((char*)d_ws + (size_t)Dq * Hq * 2);  // 2 MB fp16

  prepE<<<dim3(Dq / 32, Hq / 32), dim3(32, 8), 0, stream>>>(W, Eh);
  convV<<<(Dq * Hq / 4) / 256, 256, 0, stream>>>(V, Vh);
  nade_fwd<<<Bq / 4, 256, 0, stream>>>(x, Vh, b, (const uint32_t*)Eh, c, out);
}

// Round 15
// 758.165 us; speedup vs baseline: 1.2426x; 1.2426x over previous
//
#include <hip/hip_runtime.h>
#include <stdint.h>

#define Bq 8192
#define Dq 1024
#define Hq 1024
#define GROUP 2
#define NGROUP (Dq / GROUP)

typedef __fp16 half2_t __attribute__((ext_vector_type(2)));

static constexpr float NLOG2E = -1.4426950408889634f;

// async global->LDS, 16B/lane; lds dst is wave-uniform base (+ lane*16 by HW)
__device__ __forceinline__ void gl_lds16(const void* g, void* l) {
  __builtin_amdgcn_global_load_lds(
      (const __attribute__((address_space(1))) uint32_t*)g,
      (__attribute__((address_space(3))) uint32_t*)l, 16, 0, 0);
}

template <int CTRL>
__device__ __forceinline__ float dppadd(float v) {
  const int x = __builtin_bit_cast(int, v);
  const int y = __builtin_amdgcn_update_dpp(x, x, CTRL, 0xF, 0xF, false);
  return v + __builtin_bit_cast(float, y);
}

template <int OFF>
__device__ __forceinline__ float swzadd(float v) {
  const int y = __builtin_amdgcn_ds_swizzle(__builtin_bit_cast(int, v), OFF);
  return v + __builtin_bit_cast(float, y);
}

// EF[d][0..1023] = fp16 E = e^{-W[h][d]}, EF[d][1024..2047] = fp16 F = 1-E
__global__ __launch_bounds__(256) void prepEF(const float* __restrict__ W,
                                              __fp16* __restrict__ EF) {
  __shared__ float tile[32][33];
  const int tx = threadIdx.x, ty = threadIdx.y;
  const int bx = blockIdx.x, by = blockIdx.y;  // bx: d tile, by: h tile
#pragma unroll
  for (int i = 0; i < 4; ++i)
    tile[ty + i * 8][tx] = W[(size_t)(by * 32 + ty + i * 8) * Dq + bx * 32 + tx];
  __syncthreads();
#pragma unroll
  for (int i = 0; i < 4; ++i) {
    const int d = bx * 32 + ty + i * 8;
    const int h = by * 32 + tx;
    const float E = exp2f(tile[tx][ty + i * 8] * NLOG2E);
    EF[(size_t)d * 2048 + h] = (__fp16)E;
    EF[(size_t)d * 2048 + 1024 + h] = (__fp16)(1.0f - E);
  }
}

// Vh = fp16(V * -log2e)
__global__ __launch_bounds__(256) void convV(const float* __restrict__ V,
                                             uint32_t* __restrict__ Vh) {
  const int i = blockIdx.x * 256 + threadIdx.x;
  const float4 v = reinterpret_cast<const float4*>(V)[i];
  half2_t h0 = __builtin_amdgcn_cvt_pkrtz(v.x * NLOG2E, v.y * NLOG2E);
  half2_t h1 = __builtin_amdgcn_cvt_pkrtz(v.z * NLOG2E, v.w * NLOG2E);
  uint2 pk;
  pk.x = __builtin_bit_cast(uint32_t, h0);
  pk.y = __builtin_bit_cast(uint32_t, h1);
  reinterpret_cast<uint2*>(Vh)[i] = pk;
}

// Block = 8 batch rows (4 waves x 2). Lane owns h = 8*lane + 512*q (q=0,1).
// State: y = 1+e^{-a} (half2 x8 per batch), h = 1/y (Newton-tracked).
// Reduce: xor1+xor2 inline (DPP); xor4/8/16/32 DEFERRED, 4 chains interleaved.
__global__ __launch_bounds__(256, 4) void nade_fwd(
    const float* __restrict__ x, const uint32_t* __restrict__ Vh,
    const float* __restrict__ bvec, const uint32_t* __restrict__ EF,
    const float* __restrict__ cvec, float* __restrict__ out) {
  __shared__ __align__(16) uint32_t Vs[2][GROUP][Hq / 2];  // fp16 pairs, 8 KB
  __shared__ __align__(16) uint32_t EFs[2][GROUP][Hq];     // fp16 E|F, 16 KB

  const int tid = threadIdx.x;
  const int wave = tid >> 6;
  const int lane = tid & 63;
  const bool odd = lane & 1;
  const int b0 = blockIdx.x * 8 + wave * 2;

  // ---- init: y = 1 + 2^{c*-log2e}, h = 1/y ----
  half2_t yy[2][8], hh[2][8];
#pragma unroll
  for (int q = 0; q < 2; ++q) {
    float cv[8];
    *reinterpret_cast<float4*>(&cv[0]) =
        *reinterpret_cast<const float4*>(&cvec[512 * q + 8 * lane]);
    *reinterpret_cast<float4*>(&cv[4]) =
        *reinterpret_cast<const float4*>(&cvec[512 * q + 8 * lane + 4]);
#pragma unroll
    for (int j = 0; j < 4; ++j) {
      const float y0 = 1.0f + __builtin_amdgcn_exp2f(cv[2 * j] * NLOG2E);
      const float y1 = 1.0f + __builtin_amdgcn_exp2f(cv[2 * j + 1] * NLOG2E);
      const half2_t yp = __builtin_amdgcn_cvt_pkrtz(y0, y1);
      const half2_t hp = __builtin_amdgcn_cvt_pkrtz(
          __builtin_amdgcn_rcpf(y0), __builtin_amdgcn_rcpf(y1));
#pragma unroll
      for (int k = 0; k < 2; ++k) {
        yy[k][4 * q + j] = yp;
        hh[k][4 * q + j] = hp;
      }
    }
  }

  // ---- staging: rows [d0, d0+2): V 4KB + EF 8KB ----
  auto stage = [&](int d0, int buf) {
    gl_lds16((const char*)Vh + (size_t)d0 * 2048 + tid * 16,
             (char*)&Vs[buf][0][0] + wave * 1024);
    const char* esrc = (const char*)EF + (size_t)d0 * 4096;
#pragma unroll
    for (int q = 0; q < 2; ++q)
      gl_lds16(esrc + q * 4096 + wave * 1024 + lane * 16,
               (char*)&EFs[buf][0][0] + q * 4096 + wave * 1024);
  };

  stage(0, 0);

  unsigned long long xm0 = 0, xm1 = 0;
  float breg = 0.f;
  float s0, s1, s2, s3;
  const half2_t two2 = {(__fp16)2.0f, (__fp16)2.0f};

  __syncthreads();  // group 0 staged

// dot + inline xor1/xor2 (DPP only, no DS latency); partial -> SOUT
#define SDOT(CUR, SS, SOUT)                                                  \
  {                                                                          \
    const char* vp = (const char*)&Vs[0][0][0] + (CUR * GROUP + SS) * 2048;  \
    const uint4 v0 = *reinterpret_cast<const uint4*>(vp + 16 * lane);        \
    const uint4 v1 = *reinterpret_cast<const uint4*>(vp + 1024 + 16 * lane); \
    half2_t vh[8];                                                           \
    vh[0] = __builtin_bit_cast(half2_t, v0.x);                               \
    vh[1] = __builtin_bit_cast(half2_t, v0.y);                               \
    vh[2] = __builtin_bit_cast(half2_t, v0.z);                               \
    vh[3] = __builtin_bit_cast(half2_t, v0.w);                               \
    vh[4] = __builtin_bit_cast(half2_t, v1.x);                               \
    vh[5] = __builtin_bit_cast(half2_t, v1.y);                               \
    vh[6] = __builtin_bit_cast(half2_t, v1.z);                               \
    vh[7] = __builtin_bit_cast(half2_t, v1.w);                               \
    float dot0 = 0.f, dot1 = 0.f;                                            \
    _Pragma("unroll") for (int p = 0; p < 8; ++p) {                          \
      dot0 = __builtin_amdgcn_fdot2(hh[0][p], vh[p], dot0, false);           \
      dot1 = __builtin_amdgcn_fdot2(hh[1][p], vh[p], dot1, false);           \
    }                                                                        \
    dot0 = dppadd<0xB1>(dot0); /* xor1 */                                    \
    dot1 = dppadd<0xB1>(dot1);                                               \
    float sp = odd ? dot1 : dot0;                                            \
    sp = dppadd<0x4E>(sp); /* xor2 */                                        \
    SOUT = sp;                                                               \
  }

// gated state update (wave-uniform scalar branches)
#define SUPD(CUR, SS, DL)                                                    \
  {                                                                          \
    const uint32_t m0 = (uint32_t)(xm0 >> (DL)) & 1u;                        \
    const uint32_t m1 = (uint32_t)(xm1 >> (DL)) & 1u;                        \
    if (m0 | m1) {                                                           \
      const char* ep = (const char*)&EFs[0][0][0] + (CUR * GROUP + SS) * 4096; \
      const uint4 e0 = *reinterpret_cast<const uint4*>(ep + 16 * lane);      \
      const uint4 e1 = *reinterpret_cast<const uint4*>(ep + 1024 + 16 * lane); \
      const uint4 f0 = *reinterpret_cast<const uint4*>(ep + 2048 + 16 * lane); \
      const uint4 f1 = *reinterpret_cast<const uint4*>(ep + 3072 + 16 * lane); \
      half2_t e[8], f[8];                                                    \
      e[0] = __builtin_bit_cast(half2_t, e0.x);                              \
      e[1] = __builtin_bit_cast(half2_t, e0.y);                              \
      e[2] = __builtin_bit_cast(half2_t, e0.z);                              \
      e[3] = __builtin_bit_cast(half2_t, e0.w);                              \
      e[4] = __builtin_bit_cast(half2_t, e1.x);                              \
      e[5] = __builtin_bit_cast(half2_t, e1.y);                              \
      e[6] = __builtin_bit_cast(half2_t, e1.z);                              \
      e[7] = __builtin_bit_cast(half2_t, e1.w);                              \
      f[0] = __builtin_bit_cast(half2_t, f0.x);                              \
      f[1] = __builtin_bit_cast(half2_t, f0.y);                              \
      f[2] = __builtin_bit_cast(half2_t, f0.z);                              \
      f[3] = __builtin_bit_cast(half2_t, f0.w);                              \
      f[4] = __builtin_bit_cast(half2_t, f1.x);                              \
      f[5] = __builtin_bit_cast(half2_t, f1.y);                              \
      f[6] = __builtin_bit_cast(half2_t, f1.z);                              \
      f[7] = __builtin_bit_cast(half2_t, f1.w);                              \
      if (m0) {                                                              \
        _Pragma("unroll") for (int j = 0; j < 8; ++j) {                      \
          yy[0][j] = yy[0][j] * e[j] + f[j];                                 \
          const half2_t nt = two2 - hh[0][j] * yy[0][j];                     \
          hh[0][j] = hh[0][j] * nt;                                          \
        }                                                                    \
      }                                                                      \
      if (m1) {                                                              \
        _Pragma("unroll") for (int j = 0; j < 8; ++j) {                      \
          yy[1][j] = yy[1][j] * e[j] + f[j];                                 \
          const half2_t nt = two2 - hh[1][j] * yy[1][j];                     \
          hh[1][j] = hh[1][j] * nt;                                          \
        }                                                                    \
      }                                                                      \
    }                                                                        \
  }

  for (int gg = 0; gg < NGROUP; gg += 2) {
    const int dl0 = (2 * gg) & 63;
    // every 64 d-steps: x bitmasks via ballot (uniform), pre-scaled b row
    if ((gg & 31) == 0) {
      const float xv0 = x[(size_t)(b0 + 0) * Dq + 2 * gg + lane];
      const float xv1 = x[(size_t)(b0 + 1) * Dq + 2 * gg + lane];
      xm0 = __ballot(xv0 != 0.0f);
      xm1 = __ballot(xv1 != 0.0f);
      breg = bvec[2 * gg + lane] * NLOG2E;
    }

    stage(2 * (gg + 1), 1);  // prefetch group gg+1 -> buf1
    SDOT(0, 0, s0) SUPD(0, 0, dl0)
    SDOT(0, 1, s1) SUPD(0, 1, dl0 + 1)
    __syncthreads();  // buf1 staged; buf0 reads done

    if (gg + 2 < NGROUP) stage(2 * (gg + 2), 0);  // prefetch -> buf0
    SDOT(1, 0, s2) SUPD(1, 0, dl0 + 2)
    SDOT(1, 1, s3) SUPD(1, 1, dl0 + 3)

    // deferred reduce: 4 independent chains, level-major -> DS latencies pipeline
    s0 = swzadd<0x101F>(s0); s1 = swzadd<0x101F>(s1);
    s2 = swzadd<0x101F>(s2); s3 = swzadd<0x101F>(s3);
    s0 = swzadd<0x201F>(s0); s1 = swzadd<0x201F>(s1);
    s2 = swzadd<0x201F>(s2); s3 = swzadd<0x201F>(s3);
    s0 = swzadd<0x401F>(s0); s1 = swzadd<0x401F>(s1);
    s2 = swzadd<0x401F>(s2); s3 = swzadd<0x401F>(s3);
    s0 += __shfl_xor(s0, 32); s1 += __shfl_xor(s1, 32);
    s2 += __shfl_xor(s2, 32); s3 += __shfl_xor(s3, 32);

    const int bb = __builtin_bit_cast(int, breg);
    const float bd0 = __builtin_bit_cast(float, __builtin_amdgcn_readlane(bb, dl0));
    const float bd1 = __builtin_bit_cast(float, __builtin_amdgcn_readlane(bb, dl0 + 1));
    const float bd2 = __builtin_bit_cast(float, __builtin_amdgcn_readlane(bb, dl0 + 2));
    const float bd3 = __builtin_bit_cast(float, __builtin_amdgcn_readlane(bb, dl0 + 3));
    const float po0 = __builtin_amdgcn_rcpf(1.0f + __builtin_amdgcn_exp2f(bd0 + s0));
    const float po1 = __builtin_amdgcn_rcpf(1.0f + __builtin_amdgcn_exp2f(bd1 + s1));
    const float po2 = __builtin_amdgcn_rcpf(1.0f + __builtin_amdgcn_exp2f(bd2 + s2));
    const float po3 = __builtin_amdgcn_rcpf(1.0f + __builtin_amdgcn_exp2f(bd3 + s3));

    // coalesced output: 4 consecutive d per batch (lane0 -> b0, lane1 -> b0+1)
    if (lane < 2) {
      *reinterpret_cast<float4*>(&out[(size_t)(b0 + lane) * Dq + 2 * gg]) =
          make_float4(po0, po1, po2, po3);
    }
    __syncthreads();  // buf0 staged; buf1 reads done
  }
#undef SDOT
#undef SUPD
}

extern "C" void kernel_launch(void* const* d_in, const int* in_sizes, int n_in,
                              void* d_out, int out_size, void* d_ws, size_t ws_size,
                              hipStream_t stream) {
  (void)in_sizes; (void)n_in; (void)out_size; (void)ws_size;
  const float* x = (const float*)d_in[0];   // (B,D)
  const float* V = (const float*)d_in[1];   // (D,H)
  const float* b = (const float*)d_in[2];   // (D)
  const float* W = (const float*)d_in[3];   // (H,D)
  const float* c = (const float*)d_in[4];   // (H)
  float* out = (float*)d_out;               // (B,D)
  __fp16* EF = (__fp16*)d_ws;                              // 4 MB: E|F fp16 rows
  uint32_t* Vh = (uint32_t*)((char*)d_ws + (size_t)Dq * 4096);  // 2 MB fp16

  prepEF<<<dim3(Dq / 32, Hq / 32), dim3(32, 8), 0, stream>>>(W, EF);
  convV<<<(Dq * Hq / 4) / 256, 256, 0, stream>>>(V, Vh);
  nade_fwd<<<Bq / 8, 256, 0, stream>>>(x, Vh, b, (const uint32_t*)EF, c, out);
}